// Round 7
// baseline (78.483 us; speedup 1.0000x reference)
//
#include <hip/hip_runtime.h>

#define IMG_H 1080
#define IMG_W 1920
#define CH 3

// 16-byte payload with only 4-byte alignment guarantee (c0-1 is odd).
// gfx9+ global loads support misaligned dwordx4; LSV should emit one
// global_load_dwordx4 per quad.
struct f4u { float x, y, z, w; };

__global__ __launch_bounds__(256, 4)
void dssim_l1_kernel(const float* __restrict__ pred,
                     const float* __restrict__ gt,
                     float* __restrict__ out) {
    constexpr float K1 = 81.0f * 0.0001f;        // 81*C1
    constexpr float K2 = 81.0f * 0.0009f;        // 81*C2
    constexpr float A3 = 0.85f / 3.0f;
    constexpr float B3 = 0.15f / 3.0f;

    const int lane = threadIdx.x;                        // 0..63
    const int r    = blockIdx.y * 4 + threadIdx.y;       // output row
    const int b    = blockIdx.z;
    const int c0   = blockIdx.x * 128 + 2 * lane;        // first of 2 output cols

    const int rm = (r == 0) ? 1 : r - 1;                 // reflect rows
    const int rp = (r == IMG_H - 1) ? IMG_H - 2 : r + 1;
    const int rows[3] = { rm, r, rp };

    // load base column: quad covers c0-1 .. c0+2, clamped inside the image
    const int lc = min(max(c0 - 1, 0), IMG_W - 4);
    const bool ledge = (c0 == 0);
    const bool redge = (c0 == IMG_W - 2);

    const size_t img = (size_t)IMG_H * IMG_W;
    const float* __restrict__ xp[CH] = {
        pred + (size_t)b * CH * img,
        pred + (size_t)b * CH * img + img,
        pred + (size_t)b * CH * img + 2 * img };
    const float* __restrict__ yp[CH] = {
        gt + (size_t)b * CH * img,
        gt + (size_t)b * CH * img + img,
        gt + (size_t)b * CH * img + 2 * img };

    // ---- issue all 18 quad loads upfront (independent, fill the vmcnt queue) ----
    f4u xq[3][CH], yq[3][CH];
#pragma unroll
    for (int i = 0; i < 3; ++i) {
        const unsigned ro = (unsigned)rows[i] * IMG_W + (unsigned)lc;
#pragma unroll
        for (int c = 0; c < CH; ++c) {
            xq[i][c] = *reinterpret_cast<const f4u*>(xp[c] + ro);
            yq[i][c] = *reinterpret_cast<const f4u*>(yp[c] + ro);
        }
    }

    // ---- image-edge tap swizzle (execz-skipped for 13/15 of blocks) ----
    if (ledge || redge) {
#pragma unroll
        for (int i = 0; i < 3; ++i) {
#pragma unroll
            for (int c = 0; c < CH; ++c) {
                f4u qx = xq[i][c], qy = yq[i][c];
                if (ledge) {   // quad = cols 0..3, want (refl(-1)=1, 0, 1, 2)
                    xq[i][c].x = qx.y; xq[i][c].y = qx.x; xq[i][c].z = qx.y; xq[i][c].w = qx.z;
                    yq[i][c].x = qy.y; yq[i][c].y = qy.x; yq[i][c].z = qy.y; yq[i][c].w = qy.z;
                } else {       // quad = 1916..1919, want (1917, 1918, 1919, refl(1920)=1918)
                    xq[i][c].x = qx.y; xq[i][c].y = qx.z; xq[i][c].z = qx.w; xq[i][c].w = qx.z;
                    yq[i][c].x = qy.y; yq[i][c].y = qy.z; yq[i][c].z = qy.w; yq[i][c].w = qy.z;
                }
            }
        }
    }

    // ---- accumulate 3x3 window stats for cols A=(t0,t1,t2), B=(t1,t2,t3) ----
    float axA[CH], ayA[CH], axxA[CH], ayyA[CH], axyA[CH];
    float axB[CH], ayB[CH], axxB[CH], ayyB[CH], axyB[CH];
#pragma unroll
    for (int i = 0; i < 3; ++i) {
#pragma unroll
        for (int c = 0; c < CH; ++c) {
            const float x0 = xq[i][c].x, x1 = xq[i][c].y, x2 = xq[i][c].z, x3 = xq[i][c].w;
            const float y0 = yq[i][c].x, y1 = yq[i][c].y, y2 = yq[i][c].z, y3 = yq[i][c].w;
            // shared middle-pair partials
            const float sx  = x1 + x2;
            const float sy  = y1 + y2;
            const float sxx = fmaf(x1, x1, x2 * x2);
            const float syy = fmaf(y1, y1, y2 * y2);
            const float sxy = fmaf(x1, y1, x2 * y2);
            if (i == 0) {
                axA[c]  = sx + x0;               axB[c]  = sx + x3;
                ayA[c]  = sy + y0;               ayB[c]  = sy + y3;
                axxA[c] = fmaf(x0, x0, sxx);     axxB[c] = fmaf(x3, x3, sxx);
                ayyA[c] = fmaf(y0, y0, syy);     ayyB[c] = fmaf(y3, y3, syy);
                axyA[c] = fmaf(x0, y0, sxy);     axyB[c] = fmaf(x3, y3, sxy);
            } else {
                axA[c]  += sx + x0;              axB[c]  += sx + x3;
                ayA[c]  += sy + y0;              ayB[c]  += sy + y3;
                axxA[c] += fmaf(x0, x0, sxx);    axxB[c] += fmaf(x3, x3, sxx);
                ayyA[c] += fmaf(y0, y0, syy);    ayyB[c] += fmaf(y3, y3, syy);
                axyA[c] += fmaf(x0, y0, sxy);    axyB[c] += fmaf(x3, y3, sxy);
            }
        }
    }

    // ---- L1 term from center row (i == 1) center taps ----
    float l10 = 0.f, l11 = 0.f;
#pragma unroll
    for (int c = 0; c < CH; ++c) {
        l10 += fabsf(xq[1][c].y - yq[1][c].y);
        l11 += fabsf(xq[1][c].z - yq[1][c].z);
    }

    // ---- SSIM epilogue per output column (scaled by 81; cancels in n/d) ----
    float res0 = B3 * l10;
    float res1 = B3 * l11;
#pragma unroll
    for (int j = 0; j < 2; ++j) {
#pragma unroll
        for (int c = 0; c < CH; ++c) {
            const float ax  = j ? axB[c]  : axA[c];
            const float ay  = j ? ayB[c]  : ayA[c];
            const float axx = j ? axxB[c] : axxA[c];
            const float ayy = j ? ayyB[c] : ayyA[c];
            const float axy = j ? axyB[c] : axyA[c];

            const float u = ax * ay;
            const float v = fmaf(ay, ay, ax * ax);
            const float w = axx + ayy;
            const float num1 = fmaf(2.0f, u, K1);
            const float num2 = fmaf(18.0f, axy, fmaf(-2.0f, u, K2));
            const float den1 = v + K1;
            const float den2 = fmaf(9.0f, w, K2) - v;
            float s = fmaf(-0.5f, (num1 * num2) * __builtin_amdgcn_rcpf(den1 * den2), 0.5f);
            s = fminf(fmaxf(s, 0.0f), 1.0f);
            if (j == 0) res0 = fmaf(A3, s, res0);
            else        res1 = fmaf(A3, s, res1);
        }
    }

    float2 o; o.x = res0; o.y = res1;
    *reinterpret_cast<float2*>(out + ((size_t)b * IMG_H + r) * IMG_W + c0) = o;
}

extern "C" void kernel_launch(void* const* d_in, const int* in_sizes, int n_in,
                              void* d_out, int out_size, void* d_ws, size_t ws_size,
                              hipStream_t stream) {
    const float* pred = (const float*)d_in[0];
    const float* gt   = (const float*)d_in[1];
    float* out = (float*)d_out;

    dim3 block(64, 4, 1);
    dim3 grid(IMG_W / 128, IMG_H / 4, 4);   // 15 x 270 x 4
    dssim_l1_kernel<<<grid, block, 0, stream>>>(pred, gt, out);
}